// Round 1
// baseline (437.387 us; speedup 1.0000x reference)
//
#include <hip/hip_runtime.h>
#include <hip/hip_bf16.h>
#include <stdint.h>

#define NN 50000
#define NE 400000
#define DD 256
#define MPAD 50048   /* 391*128 */
#define EPSV 1e-5f

typedef __attribute__((ext_vector_type(8))) short bf16x8;
typedef __attribute__((ext_vector_type(4))) float f32x4;

static __device__ __forceinline__ float bf2f(unsigned short u){
  union{unsigned int i; float f;} x; x.i=((unsigned int)u)<<16; return x.f;
}
static __device__ __forceinline__ unsigned short f2bf(float f){
  union{float f; unsigned int i;} x; x.f=f;
  return (unsigned short)((x.i + 0x7FFFu + ((x.i>>16)&1u))>>16);
}
static __device__ __forceinline__ void gl_lds16(const void* g, void* l){
  __builtin_amdgcn_global_load_lds((const __attribute__((address_space(1))) void*)g,
                                   (__attribute__((address_space(3))) void*)l, 16, 0, 0);
}

/* ---------------- graph preprocessing ---------------- */

__global__ void k_degree(const int* __restrict__ ei, int* __restrict__ degi_out,
                         int* __restrict__ degi_in){
  int e = blockIdx.x*256 + threadIdx.x;
  if(e < NE){
    atomicAdd(&degi_out[ei[e]], 1);
    atomicAdd(&degi_in[ei[NE + e]], 1);
  }
}

__global__ void k_dscale(const int* __restrict__ degi_out, const int* __restrict__ degi_in,
                         float* __restrict__ dso, float* __restrict__ dsi){
  int n = blockIdx.x*256 + threadIdx.x;
  if(n < NN){
    dso[n] = rsqrtf((float)max(degi_out[n],1));
    dsi[n] = rsqrtf((float)max(degi_in[n],1));
  }
}

/* single-block exclusive scan over in-degrees -> rowptr, cursor */
__global__ void k_scan(const int* __restrict__ cnt, int* __restrict__ rowptr,
                       int* __restrict__ cursor, int n){
  __shared__ int wsum[16];
  __shared__ int s_carry;
  int tid = threadIdx.x, lane = tid & 63, wv = tid >> 6;
  if(tid==0) s_carry = 0;
  __syncthreads();
  for(int base=0; base<n; base+=1024){
    int i = base + tid;
    int v = (i<n) ? cnt[i] : 0;
    int sc = v;
    for(int off=1; off<64; off<<=1){
      int t = __shfl_up(sc, off);
      if(lane >= off) sc += t;
    }
    if(lane==63) wsum[wv] = sc;
    __syncthreads();
    if(wv==0){
      int t = (lane<16) ? wsum[lane] : 0;
      for(int off=1; off<16; off<<=1){
        int u = __shfl_up(t, off);
        if(lane >= off) t += u;
      }
      if(lane<16) wsum[lane] = t;   /* inclusive prefix of wave totals */
    }
    __syncthreads();
    int woff = (wv==0) ? 0 : wsum[wv-1];
    int carry = s_carry;
    int ex = carry + woff + sc - v;
    if(i<n){ rowptr[i] = ex; cursor[i] = ex; }
    __syncthreads();
    if(tid==0) s_carry = carry + wsum[15];
    __syncthreads();
  }
  if(tid==0) rowptr[n] = s_carry;
}

__global__ void k_fill(const int* __restrict__ ei, int* __restrict__ cursor,
                       int* __restrict__ eidx){
  int e = blockIdx.x*256 + threadIdx.x;
  if(e < NE){
    int c = ei[NE + e];
    int p = atomicAdd(&cursor[c], 1);
    eidx[p] = ei[e];
  }
}

/* W [K][Ncol] f32 -> Wt [Ncol][K] bf16 */
__global__ void k_convw(const float* __restrict__ W, unsigned short* __restrict__ Wt){
  int t = blockIdx.x*256 + threadIdx.x;   /* 65536 */
  int k = t >> 8, n = t & 255;
  Wt[n*256 + k] = f2bf(W[k*256 + n]);
}

/* hs = x * dso[row], bf16 */
__global__ void k_prep0(const float* __restrict__ x, const float* __restrict__ dso,
                        unsigned short* __restrict__ hs){
  int t = blockIdx.x*256 + threadIdx.x;   /* NN*64 */
  int row = t >> 6, c4 = (t & 63) << 2;
  if(row < NN){
    float s = dso[row];
    float4 v = *(const float4*)(x + (size_t)row*256 + c4);
    ushort4 o;
    o.x = f2bf(v.x*s); o.y = f2bf(v.y*s); o.z = f2bf(v.z*s); o.w = f2bf(v.w*s);
    *(ushort4*)(hs + (size_t)row*256 + c4) = o;
  }
}

/* one wave per destination node: agg[node] = sum over incoming edges of hs[src] */
__global__ void k_agg(const unsigned short* __restrict__ hs, const int* __restrict__ rowptr,
                      const int* __restrict__ eidx, unsigned short* __restrict__ agg){
  int node = blockIdx.x*4 + (threadIdx.x >> 6);
  int lane = threadIdx.x & 63;
  if(node >= MPAD) return;
  float a0=0.f, a1=0.f, a2=0.f, a3=0.f;
  if(node < NN){
    int s = rowptr[node], e = rowptr[node+1];
    for(int j=s; j<e; ++j){
      int src = eidx[j];
      ushort4 v = *(const ushort4*)(hs + (size_t)src*256 + (lane<<2));
      a0 += bf2f(v.x); a1 += bf2f(v.y); a2 += bf2f(v.z); a3 += bf2f(v.w);
    }
  }
  ushort4 o;
  o.x = f2bf(a0); o.y = f2bf(a1); o.z = f2bf(a2); o.w = f2bf(a3);
  *(ushort4*)(agg + (size_t)node*256 + (lane<<2)) = o;
}

/* GEMM: out[m][n] = (sum_k A[m][k]*W[k][n] + b[n]) * dsi[m] (+ hres[m][n]);
   optional fused column sum/sumsq for BatchNorm */
template<int RES, int STATS>
__global__ __launch_bounds__(256) void k_gemm(
    const unsigned short* __restrict__ A,    /* [MPAD][256] bf16 */
    const unsigned short* __restrict__ Bt,   /* [256][256] bf16 = W^T */
    const float* __restrict__ bias,
    const float* __restrict__ dsi,
    const float* __restrict__ hres,
    float* __restrict__ out,
    float* __restrict__ colsum, float* __restrict__ colsumsq)
{
  __shared__ __align__(16) unsigned char smem[32768];
  unsigned char* smA = smem;
  unsigned char* smB = smem + 16384;
  const int tid = threadIdx.x;
  const int w = tid >> 6, lane = tid & 63;
  const int m0 = blockIdx.x * 128, n0 = blockIdx.y * 128;
  const int wm = w >> 1, wn = w & 1;

  f32x4 acc[4][4];
  #pragma unroll
  for(int i=0;i<4;i++)
    #pragma unroll
    for(int j=0;j<4;j++) acc[i][j] = (f32x4){0.f,0.f,0.f,0.f};

  const char* Ab = (const char*)A;
  const char* Bb = (const char*)Bt;

  for(int kt=0; kt<4; ++kt){
    #pragma unroll
    for(int it=0; it<4; ++it){
      const int flat = w*256 + it*64 + lane;
      const int row = flat >> 3;
      const int ch  = flat & 7;
      const int sw  = ch ^ (row & 7);            /* pre-swizzled global source */
      gl_lds16(Ab + (size_t)(m0+row)*512 + kt*128 + sw*16,
               smA + (size_t)(w*256 + it*64)*16);
      gl_lds16(Bb + (size_t)(n0+row)*512 + kt*128 + sw*16,
               smB + (size_t)(w*256 + it*64)*16);
    }
    __syncthreads();
    #pragma unroll
    for(int ks=0; ks<2; ++ks){
      bf16x8 av[4], bv[4];
      #pragma unroll
      for(int f=0; f<4; ++f){
        const int ra = wm*64 + f*16 + (lane & 15);
        const int ca = ks*4 + (lane >> 4);
        av[f] = *(const bf16x8*)(smA + ra*128 + ((ca ^ (ra & 7)) << 4));
        const int rb = wn*64 + f*16 + (lane & 15);
        bv[f] = *(const bf16x8*)(smB + rb*128 + ((ca ^ (rb & 7)) << 4));
      }
      #pragma unroll
      for(int mf=0; mf<4; ++mf)
        #pragma unroll
        for(int nf=0; nf<4; ++nf)
          acc[mf][nf] = __builtin_amdgcn_mfma_f32_16x16x32_bf16(av[mf], bv[nf], acc[mf][nf], 0,0,0);
    }
    __syncthreads();
  }

  /* epilogue: C row = (lane>>4)*4+j, col = lane&15 (per 16x16 frag) */
  const int colb = n0 + wn*64 + (lane & 15);
  float bs[4];
  #pragma unroll
  for(int nf=0; nf<4; ++nf) bs[nf] = bias[colb + nf*16];
  float s[4] = {0.f,0.f,0.f,0.f}, q[4] = {0.f,0.f,0.f,0.f};
  #pragma unroll
  for(int mf=0; mf<4; ++mf){
    #pragma unroll
    for(int j=0; j<4; ++j){
      const int grow = m0 + wm*64 + mf*16 + ((lane>>4)<<2) + j;
      if(grow < NN){
        const float d = dsi[grow];
        const size_t rb = (size_t)grow * 256;
        #pragma unroll
        for(int nf=0; nf<4; ++nf){
          float v = (acc[mf][nf][j] + bs[nf]) * d;
          if(RES) v += hres[rb + colb + nf*16];
          out[rb + colb + nf*16] = v;
          if(STATS){ s[nf] += v; q[nf] += v*v; }
        }
      }
    }
  }
  if(STATS){
    #pragma unroll
    for(int nf=0; nf<4; ++nf){
      float sv = s[nf], qv = q[nf];
      sv += __shfl_xor(sv, 16); sv += __shfl_xor(sv, 32);
      qv += __shfl_xor(qv, 16); qv += __shfl_xor(qv, 32);
      if(lane < 16){
        atomicAdd(&colsum[colb + nf*16], sv);
        atomicAdd(&colsumsq[colb + nf*16], qv);
      }
    }
  }
}

__global__ void k_statsfin(const float* __restrict__ colsum, const float* __restrict__ colsumsq,
                           const float* __restrict__ g, const float* __restrict__ be,
                           float* __restrict__ cscale, float* __restrict__ cshift){
  int c = threadIdx.x;
  float mu  = colsum[c] * (1.0f/NN);
  float var = colsumsq[c] * (1.0f/NN) - mu*mu;
  var = fmaxf(var, 0.f);
  float inv = rsqrtf(var + EPSV);
  float sc = g[c] * inv;
  cscale[c] = sc;
  cshift[c] = be[c] - mu * sc;
}

/* y = relu(out*cscale+cshift); optionally keep f32 h; always emit bf16 y*dso */
template<int WRITE_F32>
__global__ void k_norm(const float* __restrict__ out, const float* __restrict__ cscale,
                       const float* __restrict__ cshift, const float* __restrict__ dso,
                       float* __restrict__ hf, unsigned short* __restrict__ hs){
  int t = blockIdx.x*256 + threadIdx.x;   /* NN*64 */
  int row = t >> 6, c4 = (t & 63) << 2;
  if(row >= NN) return;
  float4 v  = *(const float4*)(out + (size_t)row*256 + c4);
  float4 sc = *(const float4*)(cscale + c4);
  float4 sh = *(const float4*)(cshift + c4);
  float y0 = fmaxf(v.x*sc.x + sh.x, 0.f);
  float y1 = fmaxf(v.y*sc.y + sh.y, 0.f);
  float y2 = fmaxf(v.z*sc.z + sh.z, 0.f);
  float y3 = fmaxf(v.w*sc.w + sh.w, 0.f);
  if(WRITE_F32){
    float4 o = {y0,y1,y2,y3};
    *(float4*)(hf + (size_t)row*256 + c4) = o;
  }
  float s = dso[row];
  ushort4 o2;
  o2.x = f2bf(y0*s); o2.y = f2bf(y1*s); o2.z = f2bf(y2*s); o2.w = f2bf(y3*s);
  *(ushort4*)(hs + (size_t)row*256 + c4) = o2;
}

extern "C" void kernel_launch(void* const* d_in, const int* in_sizes, int n_in,
                              void* d_out, int out_size, void* d_ws, size_t ws_size,
                              hipStream_t stream){
  (void)in_sizes; (void)n_in; (void)out_size;
  const float* x  = (const float*)d_in[0];
  const int*   ei = (const int*)d_in[1];
  const float* Wl[3]  = {(const float*)d_in[2], (const float*)d_in[6], (const float*)d_in[10]};
  const float* bl[3]  = {(const float*)d_in[3], (const float*)d_in[7], (const float*)d_in[11]};
  const float* gl[2]  = {(const float*)d_in[4], (const float*)d_in[8]};
  const float* bel[2] = {(const float*)d_in[5], (const float*)d_in[9]};

  char* base = (char*)d_ws;
  size_t off = 0;
  auto alloc = [&](size_t bytes)->char* {
    char* r = base + off;
    off = (off + bytes + 511) & ~(size_t)511;
    return r;
  };
  int* degi_out = (int*)alloc((size_t)2*NN*4);
  int* degi_in  = degi_out + NN;
  float* dso    = (float*)alloc((size_t)NN*4);
  float* dsi    = (float*)alloc((size_t)NN*4);
  int* rowptr   = (int*)alloc((size_t)(NN+1)*4);
  int* cursor   = (int*)alloc((size_t)NN*4);
  int* eidx     = (int*)alloc((size_t)NE*4);
  unsigned short* Wt = (unsigned short*)alloc((size_t)3*65536*2);
  float* colsum   = (float*)alloc(2048);
  float* colsumsq = colsum + 256;
  float* cscale   = (float*)alloc(1024);
  float* cshift   = (float*)alloc(1024);
  unsigned short* hs  = (unsigned short*)alloc((size_t)MPAD*256*2);
  unsigned short* agg = (unsigned short*)alloc((size_t)MPAD*256*2);
  float* h1 = (float*)alloc((size_t)MPAD*256*4);
  float* ob = (float*)alloc((size_t)MPAD*256*4);
  if(off > ws_size) return;   /* workspace too small: fail visibly */

  /* graph prep (layer-invariant) */
  hipMemsetAsync(degi_out, 0, (size_t)2*NN*4, stream);
  k_degree<<<(NE+255)/256, 256, 0, stream>>>(ei, degi_out, degi_in);
  k_dscale<<<(NN+255)/256, 256, 0, stream>>>(degi_out, degi_in, dso, dsi);
  k_scan<<<1, 1024, 0, stream>>>(degi_in, rowptr, cursor, NN);
  k_fill<<<(NE+255)/256, 256, 0, stream>>>(ei, cursor, eidx);
  for(int l=0; l<3; ++l)
    k_convw<<<256, 256, 0, stream>>>(Wl[l], Wt + (size_t)l*65536);
  k_prep0<<<(NN*64+255)/256, 256, 0, stream>>>(x, dso, hs);

  dim3 gg(391, 2);
  /* layer 0 */
  hipMemsetAsync(colsum, 0, 2048, stream);
  k_agg<<<MPAD/4, 256, 0, stream>>>(hs, rowptr, eidx, agg);
  k_gemm<1,1><<<gg, 256, 0, stream>>>(agg, Wt, bl[0], dsi, x, ob, colsum, colsumsq);
  k_statsfin<<<1, 256, 0, stream>>>(colsum, colsumsq, gl[0], bel[0], cscale, cshift);
  k_norm<1><<<(NN*64+255)/256, 256, 0, stream>>>(ob, cscale, cshift, dso, h1, hs);
  /* layer 1 */
  hipMemsetAsync(colsum, 0, 2048, stream);
  k_agg<<<MPAD/4, 256, 0, stream>>>(hs, rowptr, eidx, agg);
  k_gemm<1,1><<<gg, 256, 0, stream>>>(agg, Wt + 65536, bl[1], dsi, h1, ob, colsum, colsumsq);
  k_statsfin<<<1, 256, 0, stream>>>(colsum, colsumsq, gl[1], bel[1], cscale, cshift);
  k_norm<0><<<(NN*64+255)/256, 256, 0, stream>>>(ob, cscale, cshift, dso, nullptr, hs);
  /* layer 2: no residual, no norm, straight to d_out */
  k_agg<<<MPAD/4, 256, 0, stream>>>(hs, rowptr, eidx, agg);
  k_gemm<0,0><<<gg, 256, 0, stream>>>(agg, Wt + 2*65536, bl[2], dsi, nullptr,
                                      (float*)d_out, nullptr, nullptr);
}

// Round 3
// 368.153 us; speedup vs baseline: 1.1881x; 1.1881x over previous
//
#include <hip/hip_runtime.h>
#include <hip/hip_bf16.h>
#include <stdint.h>

#define NN 50000
#define NE 400000
#define DD 256
#define MPAD 50048   /* 391*128 */
#define EPSV 1e-5f

typedef __attribute__((ext_vector_type(8))) short bf16x8;
typedef __attribute__((ext_vector_type(8))) unsigned short u16x8;
typedef __attribute__((ext_vector_type(4))) float f32x4;

static __device__ __forceinline__ float bf2f(unsigned short u){
  union{unsigned int i; float f;} x; x.i=((unsigned int)u)<<16; return x.f;
}
static __device__ __forceinline__ unsigned short f2bf(float f){
  union{float f; unsigned int i;} x; x.f=f;
  return (unsigned short)((x.i + 0x7FFFu + ((x.i>>16)&1u))>>16);
}
static __device__ __forceinline__ void gl_lds16(const void* g, void* l){
  __builtin_amdgcn_global_load_lds((const __attribute__((address_space(1))) void*)g,
                                   (__attribute__((address_space(3))) void*)l, 16, 0, 0);
}

/* ---------------- graph preprocessing ---------------- */

__global__ void k_degree(const int* __restrict__ ei, int* __restrict__ degi_out,
                         int* __restrict__ degi_in){
  int e = blockIdx.x*256 + threadIdx.x;
  if(e < NE){
    atomicAdd(&degi_out[ei[e]], 1);
    atomicAdd(&degi_in[ei[NE + e]], 1);
  }
}

__global__ void k_dscale(const int* __restrict__ degi_out, const int* __restrict__ degi_in,
                         float* __restrict__ dso, float* __restrict__ dsi){
  int n = blockIdx.x*256 + threadIdx.x;
  if(n < NN){
    dso[n] = rsqrtf((float)max(degi_out[n],1));
    dsi[n] = rsqrtf((float)max(degi_in[n],1));
  }
}

/* single-block exclusive scan over in-degrees -> rowptr, cursor */
__global__ void k_scan(const int* __restrict__ cnt, int* __restrict__ rowptr,
                       int* __restrict__ cursor, int n){
  __shared__ int wsum[16];
  __shared__ int s_carry;
  int tid = threadIdx.x, lane = tid & 63, wv = tid >> 6;
  if(tid==0) s_carry = 0;
  __syncthreads();
  for(int base=0; base<n; base+=1024){
    int i = base + tid;
    int v = (i<n) ? cnt[i] : 0;
    int sc = v;
    for(int off=1; off<64; off<<=1){
      int t = __shfl_up(sc, off);
      if(lane >= off) sc += t;
    }
    if(lane==63) wsum[wv] = sc;
    __syncthreads();
    if(wv==0){
      int t = (lane<16) ? wsum[lane] : 0;
      for(int off=1; off<16; off<<=1){
        int u = __shfl_up(t, off);
        if(lane >= off) t += u;
      }
      if(lane<16) wsum[lane] = t;   /* inclusive prefix of wave totals */
    }
    __syncthreads();
    int woff = (wv==0) ? 0 : wsum[wv-1];
    int carry = s_carry;
    int ex = carry + woff + sc - v;
    if(i<n){ rowptr[i] = ex; cursor[i] = ex; }
    __syncthreads();
    if(tid==0) s_carry = carry + wsum[15];
    __syncthreads();
  }
  if(tid==0) rowptr[n] = s_carry;
}

__global__ void k_fill(const int* __restrict__ ei, int* __restrict__ cursor,
                       int* __restrict__ eidx){
  int e = blockIdx.x*256 + threadIdx.x;
  if(e < NE){
    int c = ei[NE + e];
    int p = atomicAdd(&cursor[c], 1);
    eidx[p] = ei[e];
  }
}

/* W [K][Ncol] f32 -> Wt [Ncol][K] bf16 */
__global__ void k_convw(const float* __restrict__ W, unsigned short* __restrict__ Wt){
  int t = blockIdx.x*256 + threadIdx.x;   /* 65536 */
  int k = t >> 8, n = t & 255;
  Wt[n*256 + k] = f2bf(W[k*256 + n]);
}

/* hs = x * dso[row], bf16 */
__global__ void k_prep0(const float* __restrict__ x, const float* __restrict__ dso,
                        unsigned short* __restrict__ hs){
  int t = blockIdx.x*256 + threadIdx.x;   /* NN*64 */
  int row = t >> 6, c4 = (t & 63) << 2;
  if(row < NN){
    float s = dso[row];
    float4 v = *(const float4*)(x + (size_t)row*256 + c4);
    ushort4 o;
    o.x = f2bf(v.x*s); o.y = f2bf(v.y*s); o.z = f2bf(v.z*s); o.w = f2bf(v.w*s);
    *(ushort4*)(hs + (size_t)row*256 + c4) = o;
  }
}

/* one wave per destination node.
   Latency-optimized: (1) coalesced index prefetch into registers, __shfl
   broadcast; (2) half-wave split: lanes 0-31 / 32-63 each own 4 edges per
   group with 16B ushort8 gathers, issued unconditionally back-to-back
   (4 outstanding per half-wave), predicated accumulate; (3) shfl_xor(32)
   combine, lanes 0-31 store 16B. */
__global__ void k_agg(const unsigned short* __restrict__ hs, const int* __restrict__ rowptr,
                      const int* __restrict__ eidx, unsigned short* __restrict__ agg){
  int node = blockIdx.x*4 + (threadIdx.x >> 6);
  int lane = threadIdx.x & 63;
  int pair = lane >> 5, l32 = lane & 31;
  float a[8] = {0.f,0.f,0.f,0.f,0.f,0.f,0.f,0.f};
  int s = 0, e = 0;
  if(node < NN){ s = rowptr[node]; e = rowptr[node+1]; }
  int deg = e - s;
  for(int base=0; base<deg; base+=64){
    int cnt = min(deg - base, 64);
    int myidx = (base + lane < deg) ? eidx[s + base + lane] : 0;
    for(int g=0; g<cnt; g+=8){
      int jb = g + pair*4;
      int s0 = __shfl(myidx, jb+0);
      int s1 = __shfl(myidx, jb+1);
      int s2 = __shfl(myidx, jb+2);
      int s3 = __shfl(myidx, jb+3);
      /* unconditional loads: out-of-range lanes broadcast index 0 (safe) */
      u16x8 v0 = *(const u16x8*)(hs + (size_t)s0*256 + l32*8);
      u16x8 v1 = *(const u16x8*)(hs + (size_t)s1*256 + l32*8);
      u16x8 v2 = *(const u16x8*)(hs + (size_t)s2*256 + l32*8);
      u16x8 v3 = *(const u16x8*)(hs + (size_t)s3*256 + l32*8);
      if(jb+0 < cnt){
        #pragma unroll
        for(int k2=0;k2<8;k2++) a[k2] += bf2f(v0[k2]);
      }
      if(jb+1 < cnt){
        #pragma unroll
        for(int k2=0;k2<8;k2++) a[k2] += bf2f(v1[k2]);
      }
      if(jb+2 < cnt){
        #pragma unroll
        for(int k2=0;k2<8;k2++) a[k2] += bf2f(v2[k2]);
      }
      if(jb+3 < cnt){
        #pragma unroll
        for(int k2=0;k2<8;k2++) a[k2] += bf2f(v3[k2]);
      }
    }
  }
  #pragma unroll
  for(int k2=0;k2<8;k2++) a[k2] += __shfl_xor(a[k2], 32);
  if(pair==0 && node < MPAD){
    u16x8 o;
    #pragma unroll
    for(int k2=0;k2<8;k2++) o[k2] = f2bf(a[k2]);
    *(u16x8*)(agg + (size_t)node*256 + l32*8) = o;
  }
}

/* GEMM: out[m][n] = (sum_k A[m][k]*W[k][n] + b[n]) * dsi[m] (+ residual);
   optional fused column sum/sumsq for BatchNorm.
   RESMODE: 0=none, 1=f32 residual, 2=bf16 residual. OUTBF: bf16 vs f32 out. */
template<int RESMODE, int STATS, int OUTBF>
__global__ __launch_bounds__(256) void k_gemm(
    const unsigned short* __restrict__ A,    /* [MPAD][256] bf16 */
    const unsigned short* __restrict__ Bt,   /* [256][256] bf16 = W^T */
    const float* __restrict__ bias,
    const float* __restrict__ dsi,
    const float* __restrict__ resf,
    const unsigned short* __restrict__ resb,
    void* __restrict__ outp,
    float* __restrict__ colsum, float* __restrict__ colsumsq)
{
  __shared__ __align__(16) unsigned char smem[32768];
  unsigned char* smA = smem;
  unsigned char* smB = smem + 16384;
  const int tid = threadIdx.x;
  const int w = tid >> 6, lane = tid & 63;
  const int m0 = blockIdx.x * 128, n0 = blockIdx.y * 128;
  const int wm = w >> 1, wn = w & 1;

  f32x4 acc[4][4];
  #pragma unroll
  for(int i=0;i<4;i++)
    #pragma unroll
    for(int j=0;j<4;j++) acc[i][j] = (f32x4){0.f,0.f,0.f,0.f};

  const char* Ab = (const char*)A;
  const char* Bb = (const char*)Bt;

  for(int kt=0; kt<4; ++kt){
    #pragma unroll
    for(int it=0; it<4; ++it){
      const int flat = w*256 + it*64 + lane;
      const int row = flat >> 3;
      const int ch  = flat & 7;
      const int sw  = ch ^ (row & 7);            /* pre-swizzled global source */
      gl_lds16(Ab + (size_t)(m0+row)*512 + kt*128 + sw*16,
               smA + (size_t)(w*256 + it*64)*16);
      gl_lds16(Bb + (size_t)(n0+row)*512 + kt*128 + sw*16,
               smB + (size_t)(w*256 + it*64)*16);
    }
    __syncthreads();
    #pragma unroll
    for(int ks=0; ks<2; ++ks){
      bf16x8 av[4], bv[4];
      #pragma unroll
      for(int f=0; f<4; ++f){
        const int ra = wm*64 + f*16 + (lane & 15);
        const int ca = ks*4 + (lane >> 4);
        av[f] = *(const bf16x8*)(smA + ra*128 + ((ca ^ (ra & 7)) << 4));
        const int rb = wn*64 + f*16 + (lane & 15);
        bv[f] = *(const bf16x8*)(smB + rb*128 + ((ca ^ (rb & 7)) << 4));
      }
      #pragma unroll
      for(int mf=0; mf<4; ++mf)
        #pragma unroll
        for(int nf=0; nf<4; ++nf)
          acc[mf][nf] = __builtin_amdgcn_mfma_f32_16x16x32_bf16(av[mf], bv[nf], acc[mf][nf], 0,0,0);
    }
    __syncthreads();
  }

  /* epilogue: C row = (lane>>4)*4+j, col = lane&15 (per 16x16 frag) */
  const int colb = n0 + wn*64 + (lane & 15);
  float bs[4];
  #pragma unroll
  for(int nf=0; nf<4; ++nf) bs[nf] = bias[colb + nf*16];
  float s[4] = {0.f,0.f,0.f,0.f}, q[4] = {0.f,0.f,0.f,0.f};
  #pragma unroll
  for(int mf=0; mf<4; ++mf){
    #pragma unroll
    for(int j=0; j<4; ++j){
      const int grow = m0 + wm*64 + mf*16 + ((lane>>4)<<2) + j;
      if(grow < NN){
        const float d = dsi[grow];
        const size_t rb = (size_t)grow * 256;
        #pragma unroll
        for(int nf=0; nf<4; ++nf){
          float v = (acc[mf][nf][j] + bs[nf]) * d;
          if(RESMODE==1) v += resf[rb + colb + nf*16];
          if(RESMODE==2) v += bf2f(resb[rb + colb + nf*16]);
          if(OUTBF) ((unsigned short*)outp)[rb + colb + nf*16] = f2bf(v);
          else      ((float*)outp)[rb + colb + nf*16] = v;
          if(STATS){ s[nf] += v; q[nf] += v*v; }
        }
      }
    }
  }
  if(STATS){
    #pragma unroll
    for(int nf=0; nf<4; ++nf){
      float sv = s[nf], qv = q[nf];
      sv += __shfl_xor(sv, 16); sv += __shfl_xor(sv, 32);
      qv += __shfl_xor(qv, 16); qv += __shfl_xor(qv, 32);
      if(lane < 16){
        atomicAdd(&colsum[colb + nf*16], sv);
        atomicAdd(&colsumsq[colb + nf*16], qv);
      }
    }
  }
}

__global__ void k_statsfin(const float* __restrict__ colsum, const float* __restrict__ colsumsq,
                           const float* __restrict__ g, const float* __restrict__ be,
                           float* __restrict__ cscale, float* __restrict__ cshift){
  int c = threadIdx.x;
  float mu  = colsum[c] * (1.0f/NN);
  float var = colsumsq[c] * (1.0f/NN) - mu*mu;
  var = fmaxf(var, 0.f);
  float inv = rsqrtf(var + EPSV);
  float sc = g[c] * inv;
  cscale[c] = sc;
  cshift[c] = be[c] - mu * sc;
}

/* y = relu(ob*cscale+cshift); optionally keep bf16 h (residual for next layer);
   always emit bf16 y*dso (next gather source) */
template<int WRITE_H>
__global__ void k_norm(const unsigned short* __restrict__ ob, const float* __restrict__ cscale,
                       const float* __restrict__ cshift, const float* __restrict__ dso,
                       unsigned short* __restrict__ h1, unsigned short* __restrict__ hs){
  int t = blockIdx.x*256 + threadIdx.x;   /* NN*32 */
  int row = t >> 5, c8 = (t & 31) << 3;
  if(row >= NN) return;
  u16x8 v = *(const u16x8*)(ob + (size_t)row*256 + c8);
  float s = dso[row];
  u16x8 oh, os;
  #pragma unroll
  for(int k2=0;k2<8;k2++){
    float y = fmaxf(bf2f(v[k2])*cscale[c8+k2] + cshift[c8+k2], 0.f);
    oh[k2] = f2bf(y);
    os[k2] = f2bf(y*s);
  }
  if(WRITE_H) *(u16x8*)(h1 + (size_t)row*256 + c8) = oh;
  *(u16x8*)(hs + (size_t)row*256 + c8) = os;
}

extern "C" void kernel_launch(void* const* d_in, const int* in_sizes, int n_in,
                              void* d_out, int out_size, void* d_ws, size_t ws_size,
                              hipStream_t stream){
  (void)in_sizes; (void)n_in; (void)out_size;
  const float* x  = (const float*)d_in[0];
  const int*   ei = (const int*)d_in[1];
  const float* Wl[3]  = {(const float*)d_in[2], (const float*)d_in[6], (const float*)d_in[10]};
  const float* bl[3]  = {(const float*)d_in[3], (const float*)d_in[7], (const float*)d_in[11]};
  const float* gl[2]  = {(const float*)d_in[4], (const float*)d_in[8]};
  const float* bel[2] = {(const float*)d_in[5], (const float*)d_in[9]};

  char* base = (char*)d_ws;
  size_t off = 0;
  auto alloc = [&](size_t bytes)->char* {
    char* r = base + off;
    off = (off + bytes + 511) & ~(size_t)511;
    return r;
  };
  int* degi_out = (int*)alloc((size_t)2*NN*4);
  int* degi_in  = degi_out + NN;
  float* dso    = (float*)alloc((size_t)NN*4);
  float* dsi    = (float*)alloc((size_t)NN*4);
  int* rowptr   = (int*)alloc((size_t)(NN+1)*4);
  int* cursor   = (int*)alloc((size_t)NN*4);
  int* eidx     = (int*)alloc((size_t)NE*4);
  unsigned short* Wt = (unsigned short*)alloc((size_t)3*65536*2);
  float* colsum   = (float*)alloc(2048);
  float* colsumsq = colsum + 256;
  float* cscale   = (float*)alloc(1024);
  float* cshift   = (float*)alloc(1024);
  unsigned short* hs  = (unsigned short*)alloc((size_t)MPAD*256*2);
  unsigned short* agg = (unsigned short*)alloc((size_t)MPAD*256*2);
  unsigned short* h1  = (unsigned short*)alloc((size_t)MPAD*256*2);
  unsigned short* ob  = (unsigned short*)alloc((size_t)MPAD*256*2);
  if(off > ws_size) return;   /* workspace too small: fail visibly */

  /* graph prep (layer-invariant) */
  hipMemsetAsync(degi_out, 0, (size_t)2*NN*4, stream);
  k_degree<<<(NE+255)/256, 256, 0, stream>>>(ei, degi_out, degi_in);
  k_dscale<<<(NN+255)/256, 256, 0, stream>>>(degi_out, degi_in, dso, dsi);
  k_scan<<<1, 1024, 0, stream>>>(degi_in, rowptr, cursor, NN);
  k_fill<<<(NE+255)/256, 256, 0, stream>>>(ei, cursor, eidx);
  for(int l=0; l<3; ++l)
    k_convw<<<256, 256, 0, stream>>>(Wl[l], Wt + (size_t)l*65536);
  k_prep0<<<(NN*64+255)/256, 256, 0, stream>>>(x, dso, hs);

  dim3 gg(391, 2);
  /* layer 0: residual = x (f32), stats, bf16 out */
  hipMemsetAsync(colsum, 0, 2048, stream);
  k_agg<<<MPAD/4, 256, 0, stream>>>(hs, rowptr, eidx, agg);
  k_gemm<1,1,1><<<gg, 256, 0, stream>>>(agg, Wt, bl[0], dsi, x, nullptr, ob, colsum, colsumsq);
  k_statsfin<<<1, 256, 0, stream>>>(colsum, colsumsq, gl[0], bel[0], cscale, cshift);
  k_norm<1><<<(NN*32+255)/256, 256, 0, stream>>>(ob, cscale, cshift, dso, h1, hs);
  /* layer 1: residual = h1 (bf16), stats, bf16 out */
  hipMemsetAsync(colsum, 0, 2048, stream);
  k_agg<<<MPAD/4, 256, 0, stream>>>(hs, rowptr, eidx, agg);
  k_gemm<2,1,1><<<gg, 256, 0, stream>>>(agg, Wt + 65536, bl[1], dsi, nullptr, h1, ob, colsum, colsumsq);
  k_statsfin<<<1, 256, 0, stream>>>(colsum, colsumsq, gl[1], bel[1], cscale, cshift);
  k_norm<0><<<(NN*32+255)/256, 256, 0, stream>>>(ob, cscale, cshift, dso, nullptr, hs);
  /* layer 2: no residual, no norm, f32 straight to d_out */
  k_agg<<<MPAD/4, 256, 0, stream>>>(hs, rowptr, eidx, agg);
  k_gemm<0,0,0><<<gg, 256, 0, stream>>>(agg, Wt + 2*65536, bl[2], dsi, nullptr, nullptr,
                                        d_out, nullptr, nullptr);
}